// Round 8
// baseline (8796.437 us; speedup 1.0000x reference)
//
#include <hip/hip_runtime.h>

#define T_SAVE 128
#define NTH 512

typedef __attribute__((ext_vector_type(8))) short short8;
typedef __attribute__((ext_vector_type(4))) float f32x4;
typedef __attribute__((ext_vector_type(2))) float f32x2;
typedef unsigned int uint32;

__device__ __forceinline__ short f2bf(float x) {
    union { float f; unsigned u; } v; v.f = x;
    return (short)((v.u + 0x7fffu + ((v.u >> 16) & 1u)) >> 16);  // RTN-even
}
__device__ __forceinline__ float bf2f(short s) {
    union { unsigned u; float f; } v; v.u = ((unsigned)(unsigned short)s) << 16;
    return v.f;
}
__device__ __forceinline__ uint32 cvtpk_bf16(float lo, float hi) {
    uint32 r;
    asm("v_cvt_pk_bf16_f32 %0, %1, %2" : "=v"(r) : "v"(lo), "v"(hi));
    return r;
}
__device__ __forceinline__ f32x2 pk_fma(f32x2 a, f32x2 b, f32x2 c) {
    f32x2 d; asm("v_pk_fma_f32 %0, %1, %2, %3" : "=v"(d) : "v"(a), "v"(b), "v"(c)); return d;
}
__device__ __forceinline__ f32x2 pk_mul(f32x2 a, f32x2 b) {
    f32x2 d; asm("v_pk_mul_f32 %0, %1, %2" : "=v"(d) : "v"(a), "v"(b)); return d;
}
__device__ __forceinline__ float exp_negabs(float x) {
    float r; asm("v_exp_f32_e64 %0, -abs(%1)" : "=v"(r) : "v"(x)); return r;
}
#define BAR() asm volatile("s_waitcnt lgkmcnt(0)\n\ts_barrier" ::: "memory")

// softplus pair: m = x*log2e ; e = exp2(-|m|) ; q = Estrin cubic ; res = q*e + max(x,0)
__device__ __forceinline__ f32x2 softplus2(f32x2 x, f32x2 PL, f32x2 C1, f32x2 C2, f32x2 C3, f32x2 C4) {
    f32x2 m  = pk_mul(x, PL);
    f32x2 e;  e.x = exp_negabs(m.x); e.y = exp_negabs(m.y);
    f32x2 e2 = pk_mul(e, e);
    f32x2 qlo = pk_fma(C2, e, C1);
    f32x2 qhi = pk_fma(C4, e, C3);
    f32x2 q   = pk_fma(qhi, e2, qlo);
    f32x2 mx; mx.x = __builtin_fmaxf(x.x, 0.f); mx.y = __builtin_fmaxf(x.y, 0.f);
    return pk_fma(q, e, mx);
}

static __device__ const float TA[5][5] = {
    {0.161f, 0.f, 0.f, 0.f, 0.f},
    {-0.008480655492356989f, 0.335480655492357f, 0.f, 0.f, 0.f},
    {2.8971530571054935f, -6.359448489975075f, 4.3622954328695815f, 0.f, 0.f},
    {5.325864828439257f, -11.748883564062828f, 7.4955393428898365f, -0.09249506636175525f, 0.f},
    {5.86145544294642f, -12.92096931784711f, 8.159367898576159f, -0.071584973281401f, -0.028269050394068383f}
};
static __device__ const float TB[6] = {
    0.09646076681806523f, 0.01f, 0.4798896504144996f,
    1.379008574103742f, -3.290069515436081f, 2.324710524099774f
};

__global__ __launch_bounds__(NTH, 4)
void node_mfma(const float* __restrict__ ts, const float* __restrict__ y0,
               const float* __restrict__ Win, const float* __restrict__ bin,
               const float* __restrict__ Wh, const float* __restrict__ bh,
               const float* __restrict__ Wout, const float* __restrict__ bout,
               float* __restrict__ out)
{
    // 8-sample tile per block, 2 blocks/CU (grid 512). Sample slots 8-15 are
    // exact mirrors of 0-7: every lane computes a real finite trajectory,
    // mirror LDS reads hit identical addresses (broadcast, conflict-free).
    // activation buffers: chunk-major [16 chunks of 8 feats][16 slots][8 shorts]
    __shared__ __align__(16) short actA[2048];
    __shared__ __align__(16) short actB[2048];
    __shared__ __align__(16) short actC[2048];
    __shared__ __align__(16) float haccL[16 * 132];   // fp32 Hacc staging (cold path)

    const int tid  = threadIdx.x;
    const int wave = tid >> 6;
    const int lane = tid & 63;
    const int n    = lane & 15;
    const int ns   = n & 7;               // real sample index within tile (mirror)
    const int q    = lane >> 4;
    const int r    = 16 * wave + n;       // A-frag matrix row (feature)
    const int fb   = 16 * wave + 4 * q;   // features this lane's D rows cover
    const int s0   = blockIdx.x * 8;

    const int roff = lane * 8;                                           // shorts
    const int woff = (2 * wave + (q >> 1)) * 128 + n * 8 + (q & 1) * 4;  // shorts

    // ---- hidden weight fragments ----
    short8 whf0[4], whf1[4];
    #pragma unroll
    for (int c = 0; c < 4; ++c)
        #pragma unroll
        for (int j = 0; j < 8; ++j) {
            whf0[c][j] = f2bf(Wh[r * 128 + 32 * c + 8 * q + j]);
            whf1[c][j] = f2bf(Wh[16384 + r * 128 + 32 * c + 8 * q + j]);
        }

    // ---- F = Win·Wout fragments, fp32 accumulate then round (once) ----
    short8 ff[4];
    {
        float wrow[32];
        #pragma unroll
        for (int i = 0; i < 8; ++i) *(f32x4*)&wrow[4 * i] = *(const f32x4*)&Win[r * 32 + 4 * i];
        #pragma unroll 1
        for (int c = 0; c < 4; ++c) {
            float facc[8] = {0, 0, 0, 0, 0, 0, 0, 0};
            #pragma unroll
            for (int d = 0; d < 32; ++d) {
                f32x4 wa = *(const f32x4*)&Wout[d * 128 + 32 * c + 8 * q];
                f32x4 wb = *(const f32x4*)&Wout[d * 128 + 32 * c + 8 * q + 4];
                #pragma unroll
                for (int j = 0; j < 4; ++j) { facc[j] += wrow[d] * wa[j]; facc[4 + j] += wrow[d] * wb[j]; }
            }
            #pragma unroll
            for (int j = 0; j < 8; ++j) ff[c][j] = f2bf(facc[j]);
        }
    }

    // ---- c4 = (Win·bout)[fb+rr];  Yb = Win·y0[ns] + bin (projected state) ----
    float c4v[4], Yb[4];
    #pragma unroll
    for (int rr = 0; rr < 4; ++rr) {
        const float* wr = &Win[(fb + rr) * 32];
        const float* yr = &y0[(size_t)(s0 + ns) * 32];
        float cb = 0.f, yb = 0.f;
        #pragma unroll
        for (int d = 0; d < 32; ++d) { float w = wr[d]; cb += w * bout[d]; yb += w * yr[d]; }
        c4v[rr] = cb;
        Yb[rr]  = yb + bin[fb + rr];
    }
    f32x4 bhv0, bhv1, c4q;
    #pragma unroll
    for (int rr = 0; rr < 4; ++rr) {
        bhv0[rr] = bh[fb + rr]; bhv1[rr] = bh[128 + fb + rr]; c4q[rr] = c4v[rr];
    }
    const f32x4 Z4 = {0.f, 0.f, 0.f, 0.f};

    // ---- exact y (wave 0 only) + hoisted epilogue Wout hi/lo fragments ----
    float yA[4], yB[4], boA[4], boB[4];
    short8 WhiE[4][2], WloE[4][2];
    if (wave == 0) {
        f32x4 a = *(const f32x4*)&y0[(size_t)(s0 + ns) * 32 + 4 * q];
        f32x4 b = *(const f32x4*)&y0[(size_t)(s0 + ns) * 32 + 16 + 4 * q];
        #pragma unroll
        for (int rr = 0; rr < 4; ++rr) {
            yA[rr] = a[rr]; yB[rr] = b[rr];
            boA[rr] = bout[4 * q + rr]; boB[rr] = bout[16 + 4 * q + rr];
        }
        if (n < 8) {
            *(f32x4*)&out[(size_t)(s0 + n) * 4096 + 4 * q] = a;
            *(f32x4*)&out[(size_t)(s0 + n) * 4096 + 16 + 4 * q] = b;
        }
        #pragma unroll
        for (int c = 0; c < 4; ++c)
            #pragma unroll
            for (int ch = 0; ch < 2; ++ch) {
                f32x4 wa = *(const f32x4*)&Wout[(16 * ch + n) * 128 + 32 * c + 8 * q];
                f32x4 wb = *(const f32x4*)&Wout[(16 * ch + n) * 128 + 32 * c + 8 * q + 4];
                #pragma unroll
                for (int j = 0; j < 4; ++j) {
                    short h = f2bf(wa[j]); WhiE[c][ch][j] = h;     WloE[c][ch][j] = f2bf(wa[j] - bf2f(h));
                    short g = f2bf(wb[j]); WhiE[c][ch][4 + j] = g; WloE[c][ch][4 + j] = f2bf(wb[j] - bf2f(g));
                }
            }
    }

    // ---- softplus constants ----
    const f32x2 PL  = {1.44269504088896340736f, 1.44269504088896340736f};
    const f32x2 PC1 = {0.996136f, 0.996136f};
    const f32x2 PC2 = {-0.466224f, -0.466224f};
    const f32x2 PC3 = {0.218528f, 0.218528f};
    const f32x2 PC4 = {-0.055424f, -0.055424f};

    f32x2 Yb2[2] = {{Yb[0], Yb[1]}, {Yb[2], Yb[3]}};
    f32x2 zv2[6][2];
    f32x2 U0 = Yb2[0], U1 = Yb2[1];   // u for the upcoming stage (st=0: u = Yb)

    #pragma unroll 1
    for (int ti = 0; ti < T_SAVE - 1; ++ti) {
        const float hsub = (ts[ti + 1] - ts[ti]) * 0.25f;
        const f32x2 hsubp = {hsub, hsub};
        f32x2 ccp[15];
        {
            int k = 0;
            #pragma unroll
            for (int rr2 = 0; rr2 < 5; ++rr2)
                #pragma unroll
                for (int j = 0; j <= rr2; ++j) {
                    f32x2 t = {TA[rr2][j], TA[rr2][j]};
                    ccp[k++] = pk_mul(hsubp, t);
                }
        }
        f32x2 hbp[6];
        #pragma unroll
        for (int s2 = 0; s2 < 6; ++s2) { f32x2 t = {TB[s2], TB[s2]}; hbp[s2] = pk_mul(hsubp, t); }

        f32x2 HaccA = {0.f, 0.f}, HaccB = {0.f, 0.f};

        #pragma unroll 1
        for (int sub = 0; sub < 4; ++sub) {
            #pragma unroll
            for (int st = 0; st < 6; ++st) {
                // ---- seg A: softplus(u) -> actA ----
                {
                    f32x2 R0 = softplus2(U0, PL, PC1, PC2, PC3, PC4);
                    f32x2 R1 = softplus2(U1, PL, PC1, PC2, PC3, PC4);
                    uint2 pk; pk.x = cvtpk_bf16(R0.x, R0.y); pk.y = cvtpk_bf16(R1.x, R1.y);
                    *(uint2*)(actA + woff) = pk;
                }
                BAR();  // B1

                // ---- seg B: hidden 1: actA -> actB (bias in C-init, 4-acc tree) ----
                {
                    short8 b0 = *(const short8*)(actA + roff);
                    short8 b1 = *(const short8*)(actA + 512 + roff);
                    short8 b2 = *(const short8*)(actA + 1024 + roff);
                    short8 b3 = *(const short8*)(actA + 1536 + roff);
                    f32x4 A0 = __builtin_amdgcn_mfma_f32_16x16x32_bf16(whf0[0], b0, bhv0, 0, 0, 0);
                    f32x4 A1 = __builtin_amdgcn_mfma_f32_16x16x32_bf16(whf0[1], b1, Z4, 0, 0, 0);
                    f32x4 A2 = __builtin_amdgcn_mfma_f32_16x16x32_bf16(whf0[2], b2, Z4, 0, 0, 0);
                    f32x4 A3 = __builtin_amdgcn_mfma_f32_16x16x32_bf16(whf0[3], b3, Z4, 0, 0, 0);
                    f32x4 acc = (A0 + A1) + (A2 + A3);
                    f32x2 h0 = softplus2((f32x2){acc[0], acc[1]}, PL, PC1, PC2, PC3, PC4);
                    f32x2 h1 = softplus2((f32x2){acc[2], acc[3]}, PL, PC1, PC2, PC3, PC4);
                    uint2 pk; pk.x = cvtpk_bf16(h0.x, h0.y); pk.y = cvtpk_bf16(h1.x, h1.y);
                    *(uint2*)(actB + woff) = pk;
                }
                BAR();  // B2

                // ---- seg C: hidden 2: actB -> actC; shadow: u/Yb partial combine ----
                f32x2 P0, P1;
                {
                    short8 b0 = *(const short8*)(actB + roff);
                    short8 b1 = *(const short8*)(actB + 512 + roff);
                    short8 b2 = *(const short8*)(actB + 1024 + roff);
                    short8 b3 = *(const short8*)(actB + 1536 + roff);
                    // shadow-fill the ds_read wait with the already-available combine terms
                    if (st < 5) {
                        P0 = Yb2[0]; P1 = Yb2[1];
                        #pragma unroll
                        for (int j = 0; j < 5; ++j)
                            if (j < st) {
                                const int cb = st * (st + 1) / 2 + j;
                                P0 = pk_fma(ccp[cb], zv2[j][0], P0);
                                P1 = pk_fma(ccp[cb], zv2[j][1], P1);
                            }
                    } else {
                        f32x2 tb0 = {TB[0], TB[0]};
                        P0 = pk_mul(tb0, zv2[0][0]); P1 = pk_mul(tb0, zv2[0][1]);
                        #pragma unroll
                        for (int j = 1; j < 5; ++j) {
                            f32x2 tbj = {TB[j], TB[j]};
                            P0 = pk_fma(tbj, zv2[j][0], P0);
                            P1 = pk_fma(tbj, zv2[j][1], P1);
                        }
                    }
                    f32x4 A0 = __builtin_amdgcn_mfma_f32_16x16x32_bf16(whf1[0], b0, bhv1, 0, 0, 0);
                    f32x4 A1 = __builtin_amdgcn_mfma_f32_16x16x32_bf16(whf1[1], b1, Z4, 0, 0, 0);
                    f32x4 A2 = __builtin_amdgcn_mfma_f32_16x16x32_bf16(whf1[2], b2, Z4, 0, 0, 0);
                    f32x4 A3 = __builtin_amdgcn_mfma_f32_16x16x32_bf16(whf1[3], b3, Z4, 0, 0, 0);
                    f32x4 acc = (A0 + A1) + (A2 + A3);
                    f32x2 h3L = softplus2((f32x2){acc[0], acc[1]}, PL, PC1, PC2, PC3, PC4);
                    f32x2 h3H = softplus2((f32x2){acc[2], acc[3]}, PL, PC1, PC2, PC3, PC4);
                    HaccA = pk_fma(hbp[st], h3L, HaccA);
                    HaccB = pk_fma(hbp[st], h3H, HaccB);
                    uint2 pk; pk.x = cvtpk_bf16(h3L.x, h3L.y); pk.y = cvtpk_bf16(h3H.x, h3H.y);
                    *(uint2*)(actC + woff) = pk;
                }
                BAR();  // B3

                // ---- seg D: fused layer z = F·h3 + c4 (C-init); finish u / Yb ----
                {
                    short8 b0 = *(const short8*)(actC + roff);
                    short8 b1 = *(const short8*)(actC + 512 + roff);
                    short8 b2 = *(const short8*)(actC + 1024 + roff);
                    short8 b3 = *(const short8*)(actC + 1536 + roff);
                    f32x4 A0 = __builtin_amdgcn_mfma_f32_16x16x32_bf16(ff[0], b0, c4q, 0, 0, 0);
                    f32x4 A1 = __builtin_amdgcn_mfma_f32_16x16x32_bf16(ff[1], b1, Z4, 0, 0, 0);
                    f32x4 A2 = __builtin_amdgcn_mfma_f32_16x16x32_bf16(ff[2], b2, Z4, 0, 0, 0);
                    f32x4 A3 = __builtin_amdgcn_mfma_f32_16x16x32_bf16(ff[3], b3, Z4, 0, 0, 0);
                    f32x4 acc = (A0 + A1) + (A2 + A3);
                    f32x2 zL = {acc[0], acc[1]};
                    f32x2 zH = {acc[2], acc[3]};
                    zv2[st][0] = zL; zv2[st][1] = zH;
                    if (st < 5) {
                        const int cb = st * (st + 1) / 2 + st;
                        U0 = pk_fma(ccp[cb], zL, P0);
                        U1 = pk_fma(ccp[cb], zH, P1);
                    } else {
                        f32x2 tb5 = {TB[5], TB[5]};
                        P0 = pk_fma(tb5, zL, P0); P1 = pk_fma(tb5, zH, P1);
                        Yb2[0] = pk_fma(hsubp, P0, Yb2[0]);
                        Yb2[1] = pk_fma(hsubp, P1, Yb2[1]);
                        U0 = Yb2[0]; U1 = Yb2[1];
                    }
                }
            }
        }

        // ---- interval end: y += Wout·Hacc_total + 4h·bout (wave 0, hi/lo exact) ----
        {
            f32x4 hv; hv[0] = HaccA.x; hv[1] = HaccA.y; hv[2] = HaccB.x; hv[3] = HaccB.y;
            *(f32x4*)(haccL + n * 132 + fb) = hv;
        }
        BAR();
        if (wave == 0) {
            f32x4 d0 = {0.f, 0.f, 0.f, 0.f};
            f32x4 d1 = {0.f, 0.f, 0.f, 0.f};
            #pragma unroll
            for (int c = 0; c < 4; ++c) {
                f32x4 ha = *(const f32x4*)(haccL + n * 132 + 32 * c + 8 * q);
                f32x4 hb2 = *(const f32x4*)(haccL + n * 132 + 32 * c + 8 * q + 4);
                short8 Hhi, Hlo;
                #pragma unroll
                for (int j = 0; j < 4; ++j) {
                    short h = f2bf(ha[j]);  Hhi[j] = h;     Hlo[j] = f2bf(ha[j] - bf2f(h));
                    short g = f2bf(hb2[j]); Hhi[4 + j] = g; Hlo[4 + j] = f2bf(hb2[j] - bf2f(g));
                }
                #pragma unroll
                for (int ch = 0; ch < 2; ++ch) {
                    f32x4 dd = ch ? d1 : d0;
                    dd = __builtin_amdgcn_mfma_f32_16x16x32_bf16(WhiE[c][ch], Hhi, dd, 0, 0, 0);
                    dd = __builtin_amdgcn_mfma_f32_16x16x32_bf16(WhiE[c][ch], Hlo, dd, 0, 0, 0);
                    dd = __builtin_amdgcn_mfma_f32_16x16x32_bf16(WloE[c][ch], Hhi, dd, 0, 0, 0);
                    if (ch) d1 = dd; else d0 = dd;
                }
            }
            const float hb4 = 4.f * hsub;
            #pragma unroll
            for (int rr = 0; rr < 4; ++rr) {
                yA[rr] += d0[rr] + hb4 * boA[rr];
                yB[rr] += d1[rr] + hb4 * boB[rr];
            }
            if (n < 8) {
                f32x4 oa, ob;
                #pragma unroll
                for (int rr = 0; rr < 4; ++rr) { oa[rr] = yA[rr]; ob[rr] = yB[rr]; }
                *(f32x4*)&out[(size_t)(s0 + n) * 4096 + (ti + 1) * 32 + 4 * q] = oa;
                *(f32x4*)&out[(size_t)(s0 + n) * 4096 + (ti + 1) * 32 + 16 + 4 * q] = ob;
            }
        }
    }
}

extern "C" void kernel_launch(void* const* d_in, const int* in_sizes, int n_in,
                              void* d_out, int out_size, void* d_ws, size_t ws_size,
                              hipStream_t stream) {
    const float* ts   = (const float*)d_in[0];
    const float* y0   = (const float*)d_in[1];
    const float* Win  = (const float*)d_in[2];
    const float* bin  = (const float*)d_in[3];
    const float* Wh   = (const float*)d_in[4];
    const float* bh   = (const float*)d_in[5];
    const float* Wout = (const float*)d_in[6];
    const float* bout = (const float*)d_in[7];
    float* out = (float*)d_out;

    const int Btot = in_sizes[1] / 32;  // 4096 samples
    dim3 grid(Btot / 8), block(NTH);    // 512 blocks x 512 threads, 2 blocks/CU
    node_mfma<<<grid, block, 0, stream>>>(ts, y0, Win, bin, Wh, bh, Wout, bout, out);
}

// Round 9
// 5087.299 us; speedup vs baseline: 1.7291x; 1.7291x over previous
//
#include <hip/hip_runtime.h>

#define T_SAVE 128
#define NTH 512

typedef __attribute__((ext_vector_type(8))) short short8;
typedef __attribute__((ext_vector_type(4))) float f32x4;
typedef __attribute__((ext_vector_type(2))) float f32x2;
typedef unsigned int uint32;

__device__ __forceinline__ short f2bf(float x) {
    union { float f; unsigned u; } v; v.f = x;
    return (short)((v.u + 0x7fffu + ((v.u >> 16) & 1u)) >> 16);  // RTN-even
}
__device__ __forceinline__ float bf2f(short s) {
    union { unsigned u; float f; } v; v.u = ((unsigned)(unsigned short)s) << 16;
    return v.f;
}
__device__ __forceinline__ uint32 cvtpk_bf16(float lo, float hi) {
    uint32 r;
    asm("v_cvt_pk_bf16_f32 %0, %1, %2" : "=v"(r) : "v"(lo), "v"(hi));
    return r;
}
__device__ __forceinline__ f32x2 pk_fma(f32x2 a, f32x2 b, f32x2 c) {
    f32x2 d; asm("v_pk_fma_f32 %0, %1, %2, %3" : "=v"(d) : "v"(a), "v"(b), "v"(c)); return d;
}
__device__ __forceinline__ f32x2 pk_mul(f32x2 a, f32x2 b) {
    f32x2 d; asm("v_pk_mul_f32 %0, %1, %2" : "=v"(d) : "v"(a), "v"(b)); return d;
}
__device__ __forceinline__ float exp_negabs(float x) {
    float r; asm("v_exp_f32_e64 %0, -abs(%1)" : "=v"(r) : "v"(x)); return r;
}
#define BAR() asm volatile("s_waitcnt lgkmcnt(0)\n\ts_barrier" ::: "memory")

// softplus pair: m = x*log2e ; e = exp2(-|m|) ; q = Estrin cubic ; res = q*e + max(x,0)
__device__ __forceinline__ f32x2 softplus2(f32x2 x, f32x2 PL, f32x2 C1, f32x2 C2, f32x2 C3, f32x2 C4) {
    f32x2 m  = pk_mul(x, PL);
    f32x2 e;  e.x = exp_negabs(m.x); e.y = exp_negabs(m.y);
    f32x2 e2 = pk_mul(e, e);
    f32x2 qlo = pk_fma(C2, e, C1);
    f32x2 qhi = pk_fma(C4, e, C3);
    f32x2 q   = pk_fma(qhi, e2, qlo);
    f32x2 mx; mx.x = __builtin_fmaxf(x.x, 0.f); mx.y = __builtin_fmaxf(x.y, 0.f);
    return pk_fma(q, e, mx);
}

static __device__ const float TA[5][5] = {
    {0.161f, 0.f, 0.f, 0.f, 0.f},
    {-0.008480655492356989f, 0.335480655492357f, 0.f, 0.f, 0.f},
    {2.8971530571054935f, -6.359448489975075f, 4.3622954328695815f, 0.f, 0.f},
    {5.325864828439257f, -11.748883564062828f, 7.4955393428898365f, -0.09249506636175525f, 0.f},
    {5.86145544294642f, -12.92096931784711f, 8.159367898576159f, -0.071584973281401f, -0.028269050394068383f}
};
static __device__ const float TB[6] = {
    0.09646076681806523f, 0.01f, 0.4798896504144996f,
    1.379008574103742f, -3.290069515436081f, 2.324710524099774f
};

// ---- per-group segment macros (G = X or Y) -------------------------------
#define SEGA(G) do {                                                          \
    f32x2 R0 = softplus2(U0##G, PL, PC1, PC2, PC3, PC4);                      \
    f32x2 R1 = softplus2(U1##G, PL, PC1, PC2, PC3, PC4);                      \
    uint2 pk; pk.x = cvtpk_bf16(R0.x, R0.y); pk.y = cvtpk_bf16(R1.x, R1.y);   \
    *(uint2*)(act##G##A + woff) = pk;                                         \
} while (0)

#define SEGB(G) do {                                                          \
    short8 b0 = *(const short8*)(act##G##A + roff);                           \
    short8 b1 = *(const short8*)(act##G##A + 512 + roff);                     \
    short8 b2 = *(const short8*)(act##G##A + 1024 + roff);                    \
    short8 b3 = *(const short8*)(act##G##A + 1536 + roff);                    \
    f32x4 A0 = __builtin_amdgcn_mfma_f32_16x16x32_bf16(whf0[0], b0, bhv0, 0, 0, 0); \
    f32x4 A1 = __builtin_amdgcn_mfma_f32_16x16x32_bf16(whf0[1], b1, Z4, 0, 0, 0);   \
    f32x4 A2 = __builtin_amdgcn_mfma_f32_16x16x32_bf16(whf0[2], b2, Z4, 0, 0, 0);   \
    f32x4 A3 = __builtin_amdgcn_mfma_f32_16x16x32_bf16(whf0[3], b3, Z4, 0, 0, 0);   \
    f32x4 acc = (A0 + A1) + (A2 + A3);                                        \
    f32x2 h0 = softplus2((f32x2){acc[0], acc[1]}, PL, PC1, PC2, PC3, PC4);    \
    f32x2 h1 = softplus2((f32x2){acc[2], acc[3]}, PL, PC1, PC2, PC3, PC4);    \
    uint2 pk; pk.x = cvtpk_bf16(h0.x, h0.y); pk.y = cvtpk_bf16(h1.x, h1.y);   \
    *(uint2*)(act##G##B + woff) = pk;                                         \
} while (0)

#define SEGC(G) do {                                                          \
    short8 b0 = *(const short8*)(act##G##B + roff);                           \
    short8 b1 = *(const short8*)(act##G##B + 512 + roff);                     \
    short8 b2 = *(const short8*)(act##G##B + 1024 + roff);                    \
    short8 b3 = *(const short8*)(act##G##B + 1536 + roff);                    \
    /* shadow: partial combine for next u / Yb, fills the ds_read wait */     \
    if (st < 5) {                                                             \
        P0##G = Yb0##G; P1##G = Yb1##G;                                       \
        _Pragma("unroll")                                                     \
        for (int j = 0; j < 5; ++j)                                           \
            if (j < st) {                                                     \
                f32x2 t = {TA[st][j], TA[st][j]};                             \
                f32x2 c = pk_mul(hsubp, t);                                   \
                P0##G = pk_fma(c, zv##G[j][0], P0##G);                        \
                P1##G = pk_fma(c, zv##G[j][1], P1##G);                        \
            }                                                                 \
    } else {                                                                  \
        f32x2 tb0 = {TB[0], TB[0]};                                           \
        P0##G = pk_mul(tb0, zv##G[0][0]); P1##G = pk_mul(tb0, zv##G[0][1]);   \
        _Pragma("unroll")                                                     \
        for (int j = 1; j < 5; ++j) {                                         \
            f32x2 tbj = {TB[j], TB[j]};                                       \
            P0##G = pk_fma(tbj, zv##G[j][0], P0##G);                          \
            P1##G = pk_fma(tbj, zv##G[j][1], P1##G);                          \
        }                                                                     \
    }                                                                         \
    f32x4 A0 = __builtin_amdgcn_mfma_f32_16x16x32_bf16(whf1[0], b0, bhv1, 0, 0, 0); \
    f32x4 A1 = __builtin_amdgcn_mfma_f32_16x16x32_bf16(whf1[1], b1, Z4, 0, 0, 0);   \
    f32x4 A2 = __builtin_amdgcn_mfma_f32_16x16x32_bf16(whf1[2], b2, Z4, 0, 0, 0);   \
    f32x4 A3 = __builtin_amdgcn_mfma_f32_16x16x32_bf16(whf1[3], b3, Z4, 0, 0, 0);   \
    f32x4 acc = (A0 + A1) + (A2 + A3);                                        \
    f32x2 h3L = softplus2((f32x2){acc[0], acc[1]}, PL, PC1, PC2, PC3, PC4);   \
    f32x2 h3H = softplus2((f32x2){acc[2], acc[3]}, PL, PC1, PC2, PC3, PC4);   \
    { f32x2 tb = {TB[st], TB[st]}; f32x2 hb = pk_mul(hsubp, tb);              \
      Ha##G = pk_fma(hb, h3L, Ha##G); Hb##G = pk_fma(hb, h3H, Hb##G); }       \
    uint2 pk; pk.x = cvtpk_bf16(h3L.x, h3L.y); pk.y = cvtpk_bf16(h3H.x, h3H.y); \
    *(uint2*)(act##G##C + woff) = pk;                                         \
} while (0)

#define SEGD(G) do {                                                          \
    short8 b0 = *(const short8*)(act##G##C + roff);                           \
    short8 b1 = *(const short8*)(act##G##C + 512 + roff);                     \
    short8 b2 = *(const short8*)(act##G##C + 1024 + roff);                    \
    short8 b3 = *(const short8*)(act##G##C + 1536 + roff);                    \
    f32x4 A0 = __builtin_amdgcn_mfma_f32_16x16x32_bf16(ff[0], b0, c4q, 0, 0, 0); \
    f32x4 A1 = __builtin_amdgcn_mfma_f32_16x16x32_bf16(ff[1], b1, Z4, 0, 0, 0);  \
    f32x4 A2 = __builtin_amdgcn_mfma_f32_16x16x32_bf16(ff[2], b2, Z4, 0, 0, 0);  \
    f32x4 A3 = __builtin_amdgcn_mfma_f32_16x16x32_bf16(ff[3], b3, Z4, 0, 0, 0);  \
    f32x4 acc = (A0 + A1) + (A2 + A3);                                        \
    f32x2 zL = {acc[0], acc[1]};                                              \
    f32x2 zH = {acc[2], acc[3]};                                              \
    zv##G[st][0] = zL; zv##G[st][1] = zH;                                     \
    if (st < 5) {                                                             \
        f32x2 t = {TA[st][st], TA[st][st]};                                   \
        f32x2 c = pk_mul(hsubp, t);                                           \
        U0##G = pk_fma(c, zL, P0##G);                                         \
        U1##G = pk_fma(c, zH, P1##G);                                         \
    } else {                                                                  \
        f32x2 tb5 = {TB[5], TB[5]};                                           \
        P0##G = pk_fma(tb5, zL, P0##G); P1##G = pk_fma(tb5, zH, P1##G);       \
        Yb0##G = pk_fma(hsubp, P0##G, Yb0##G);                                \
        Yb1##G = pk_fma(hsubp, P1##G, Yb1##G);                                \
        U0##G = Yb0##G; U1##G = Yb1##G;                                       \
    }                                                                         \
} while (0)

__global__ __launch_bounds__(NTH, 1)
void node_mfma(const float* __restrict__ ts, const float* __restrict__ y0,
               const float* __restrict__ Win, const float* __restrict__ bin,
               const float* __restrict__ Wh, const float* __restrict__ bh,
               const float* __restrict__ Wout, const float* __restrict__ bout,
               float* __restrict__ out)
{
    // two independent half-width chains: X = samples 0-7, Y = samples 8-15.
    // each has private act buffers [16 chunks][16 sample slots][8 shorts]
    // (slots 8-15 hold a mirrored duplicate so all lanes stay finite).
    // __launch_bounds__(512,1): min-blocks semantics -> 256-VGPR cap, no spill.
    __shared__ __align__(16) short actXA[2048], actXB[2048], actXC[2048];
    __shared__ __align__(16) short actYA[2048], actYB[2048], actYC[2048];
    __shared__ __align__(16) float haccL[16 * 132];

    const int tid  = threadIdx.x;
    const int wave = tid >> 6;
    const int lane = tid & 63;
    const int n    = lane & 15;
    const int nx   = n & 7;               // mirrored sample index within group
    const int q    = lane >> 4;
    const int r    = 16 * wave + n;       // A-frag matrix row (feature)
    const int fb   = 16 * wave + 4 * q;   // features this lane's D rows cover
    const int s0   = blockIdx.x * 16;

    const int roff = lane * 8;                                           // shorts
    const int woff = (2 * wave + (q >> 1)) * 128 + n * 8 + (q & 1) * 4;  // shorts

    // ---- hidden weight fragments (shared by both groups) ----
    short8 whf0[4], whf1[4];
    #pragma unroll
    for (int c = 0; c < 4; ++c)
        #pragma unroll
        for (int j = 0; j < 8; ++j) {
            whf0[c][j] = f2bf(Wh[r * 128 + 32 * c + 8 * q + j]);
            whf1[c][j] = f2bf(Wh[16384 + r * 128 + 32 * c + 8 * q + j]);
        }

    // ---- F = Win·Wout fragments ----
    short8 ff[4];
    {
        float wrow[32];
        #pragma unroll
        for (int i = 0; i < 8; ++i) *(f32x4*)&wrow[4 * i] = *(const f32x4*)&Win[r * 32 + 4 * i];
        #pragma unroll 1
        for (int c = 0; c < 4; ++c) {
            float facc[8] = {0, 0, 0, 0, 0, 0, 0, 0};
            #pragma unroll
            for (int d = 0; d < 32; ++d) {
                f32x4 wa = *(const f32x4*)&Wout[d * 128 + 32 * c + 8 * q];
                f32x4 wb = *(const f32x4*)&Wout[d * 128 + 32 * c + 8 * q + 4];
                #pragma unroll
                for (int j = 0; j < 4; ++j) { facc[j] += wrow[d] * wa[j]; facc[4 + j] += wrow[d] * wb[j]; }
            }
            #pragma unroll
            for (int j = 0; j < 8; ++j) ff[c][j] = f2bf(facc[j]);
        }
    }

    // ---- c4 = (Win·bout)[fb+rr]; Yb per group (X: sample s0+nx, Y: s0+8+nx) ----
    float c4v[4], YbXs[4], YbYs[4];
    {
        const float* yrX = &y0[(size_t)(s0 + nx) * 32];
        const float* yrY = &y0[(size_t)(s0 + 8 + nx) * 32];
        #pragma unroll
        for (int rr = 0; rr < 4; ++rr) {
            const float* wr = &Win[(fb + rr) * 32];
            float cb = 0.f, ybx = 0.f, yby = 0.f;
            #pragma unroll
            for (int d = 0; d < 32; ++d) {
                float w = wr[d]; cb += w * bout[d]; ybx += w * yrX[d]; yby += w * yrY[d];
            }
            c4v[rr]  = cb;
            YbXs[rr] = ybx + bin[fb + rr];
            YbYs[rr] = yby + bin[fb + rr];
        }
    }
    f32x4 bhv0, bhv1, c4q;
    #pragma unroll
    for (int rr = 0; rr < 4; ++rr) {
        bhv0[rr] = bh[fb + rr]; bhv1[rr] = bh[128 + fb + rr]; c4q[rr] = c4v[rr];
    }
    const f32x4 Z4 = {0.f, 0.f, 0.f, 0.f};

    // ---- exact y (wave 0 only) + hoisted epilogue Wout hi/lo fragments ----
    float yA[4], yB[4], boA[4], boB[4];
    short8 WhiE[4][2], WloE[4][2];
    if (wave == 0) {
        f32x4 a = *(const f32x4*)&y0[(size_t)(s0 + n) * 32 + 4 * q];
        f32x4 b = *(const f32x4*)&y0[(size_t)(s0 + n) * 32 + 16 + 4 * q];
        #pragma unroll
        for (int rr = 0; rr < 4; ++rr) {
            yA[rr] = a[rr]; yB[rr] = b[rr];
            boA[rr] = bout[4 * q + rr]; boB[rr] = bout[16 + 4 * q + rr];
        }
        *(f32x4*)&out[(size_t)(s0 + n) * 4096 + 4 * q] = a;
        *(f32x4*)&out[(size_t)(s0 + n) * 4096 + 16 + 4 * q] = b;
        #pragma unroll
        for (int c = 0; c < 4; ++c)
            #pragma unroll
            for (int ch = 0; ch < 2; ++ch) {
                f32x4 wa = *(const f32x4*)&Wout[(16 * ch + n) * 128 + 32 * c + 8 * q];
                f32x4 wb = *(const f32x4*)&Wout[(16 * ch + n) * 128 + 32 * c + 8 * q + 4];
                #pragma unroll
                for (int j = 0; j < 4; ++j) {
                    short h = f2bf(wa[j]); WhiE[c][ch][j] = h;     WloE[c][ch][j] = f2bf(wa[j] - bf2f(h));
                    short g = f2bf(wb[j]); WhiE[c][ch][4 + j] = g; WloE[c][ch][4 + j] = f2bf(wb[j] - bf2f(g));
                }
            }
    }

    // ---- softplus constants ----
    const f32x2 PL  = {1.44269504088896340736f, 1.44269504088896340736f};
    const f32x2 PC1 = {0.996136f, 0.996136f};
    const f32x2 PC2 = {-0.466224f, -0.466224f};
    const f32x2 PC3 = {0.218528f, 0.218528f};
    const f32x2 PC4 = {-0.055424f, -0.055424f};

    // ---- per-group state ----
    f32x2 Yb0X = {YbXs[0], YbXs[1]}, Yb1X = {YbXs[2], YbXs[3]};
    f32x2 Yb0Y = {YbYs[0], YbYs[1]}, Yb1Y = {YbYs[2], YbYs[3]};
    f32x2 zvX[6][2], zvY[6][2];
    f32x2 U0X = Yb0X, U1X = Yb1X;
    f32x2 U0Y = Yb0Y, U1Y = Yb1Y;

    #pragma unroll 1
    for (int ti = 0; ti < T_SAVE - 1; ++ti) {
        const float hsub = (ts[ti + 1] - ts[ti]) * 0.25f;
        const f32x2 hsubp = {hsub, hsub};
        f32x2 HaX = {0.f, 0.f}, HbX = {0.f, 0.f};
        f32x2 HaY = {0.f, 0.f}, HbY = {0.f, 0.f};

        #pragma unroll 1
        for (int sub = 0; sub < 4; ++sub) {
            #pragma unroll
            for (int st = 0; st < 6; ++st) {
                SEGA(X); SEGA(Y);
                BAR();  // B1
                SEGB(X); SEGB(Y);
                BAR();  // B2
                f32x2 P0X, P1X, P0Y, P1Y;
                SEGC(X); SEGC(Y);
                BAR();  // B3
                SEGD(X); SEGD(Y);
            }
        }

        // ---- interval end: lane picks its own group's Hacc; epilogue as before ----
        {
            f32x2 sA = (n < 8) ? HaX : HaY;
            f32x2 sB = (n < 8) ? HbX : HbY;
            f32x4 hv; hv[0] = sA.x; hv[1] = sA.y; hv[2] = sB.x; hv[3] = sB.y;
            *(f32x4*)(haccL + n * 132 + fb) = hv;
        }
        BAR();
        if (wave == 0) {
            f32x4 d0 = {0.f, 0.f, 0.f, 0.f};
            f32x4 d1 = {0.f, 0.f, 0.f, 0.f};
            #pragma unroll
            for (int c = 0; c < 4; ++c) {
                f32x4 ha = *(const f32x4*)(haccL + n * 132 + 32 * c + 8 * q);
                f32x4 hb2 = *(const f32x4*)(haccL + n * 132 + 32 * c + 8 * q + 4);
                short8 Hhi, Hlo;
                #pragma unroll
                for (int j = 0; j < 4; ++j) {
                    short h = f2bf(ha[j]);  Hhi[j] = h;     Hlo[j] = f2bf(ha[j] - bf2f(h));
                    short g = f2bf(hb2[j]); Hhi[4 + j] = g; Hlo[4 + j] = f2bf(hb2[j] - bf2f(g));
                }
                #pragma unroll
                for (int ch = 0; ch < 2; ++ch) {
                    f32x4 dd = ch ? d1 : d0;
                    dd = __builtin_amdgcn_mfma_f32_16x16x32_bf16(WhiE[c][ch], Hhi, dd, 0, 0, 0);
                    dd = __builtin_amdgcn_mfma_f32_16x16x32_bf16(WhiE[c][ch], Hlo, dd, 0, 0, 0);
                    dd = __builtin_amdgcn_mfma_f32_16x16x32_bf16(WloE[c][ch], Hhi, dd, 0, 0, 0);
                    if (ch) d1 = dd; else d0 = dd;
                }
            }
            const float hb4 = 4.f * hsub;
            f32x4 oa, ob;
            #pragma unroll
            for (int rr = 0; rr < 4; ++rr) {
                yA[rr] += d0[rr] + hb4 * boA[rr];
                yB[rr] += d1[rr] + hb4 * boB[rr];
                oa[rr] = yA[rr]; ob[rr] = yB[rr];
            }
            *(f32x4*)&out[(size_t)(s0 + n) * 4096 + (ti + 1) * 32 + 4 * q] = oa;
            *(f32x4*)&out[(size_t)(s0 + n) * 4096 + (ti + 1) * 32 + 16 + 4 * q] = ob;
        }
    }
}

extern "C" void kernel_launch(void* const* d_in, const int* in_sizes, int n_in,
                              void* d_out, int out_size, void* d_ws, size_t ws_size,
                              hipStream_t stream) {
    const float* ts   = (const float*)d_in[0];
    const float* y0   = (const float*)d_in[1];
    const float* Win  = (const float*)d_in[2];
    const float* bin  = (const float*)d_in[3];
    const float* Wh   = (const float*)d_in[4];
    const float* bh   = (const float*)d_in[5];
    const float* Wout = (const float*)d_in[6];
    const float* bout = (const float*)d_in[7];
    float* out = (float*)d_out;

    const int Btot = in_sizes[1] / 32;  // 4096 samples
    dim3 grid(Btot / 16), block(NTH);   // 256 blocks x 512 threads, 1 block/CU
    node_mfma<<<grid, block, 0, stream>>>(ts, y0, Win, bin, Wh, bh, Wout, bout, out);
}

// Round 11
// 2763.848 us; speedup vs baseline: 3.1827x; 1.8407x over previous
//
#include <hip/hip_runtime.h>

#define T_SAVE 128
#define NTH 512

typedef __attribute__((ext_vector_type(8))) short short8;
typedef __attribute__((ext_vector_type(4))) float f32x4;
typedef __attribute__((ext_vector_type(2))) float f32x2;
typedef unsigned int uint32;

__device__ __forceinline__ short f2bf(float x) {
    union { float f; unsigned u; } v; v.f = x;
    return (short)((v.u + 0x7fffu + ((v.u >> 16) & 1u)) >> 16);  // RTN-even
}
__device__ __forceinline__ float bf2f(short s) {
    union { unsigned u; float f; } v; v.u = ((unsigned)(unsigned short)s) << 16;
    return v.f;
}
// one-instruction pack: dst.lo16 = bf16(lo), dst.hi16 = bf16(hi), RNE
__device__ __forceinline__ uint32 cvtpk_bf16(float lo, float hi) {
    uint32 r;
    asm("v_cvt_pk_bf16_f32 %0, %1, %2" : "=v"(r) : "v"(lo), "v"(hi));
    return r;
}
// packed dual-FP32 VALU (CDNA double-rate fp32)
__device__ __forceinline__ f32x2 pk_fma(f32x2 a, f32x2 b, f32x2 c) {
    f32x2 d; asm("v_pk_fma_f32 %0, %1, %2, %3" : "=v"(d) : "v"(a), "v"(b), "v"(c)); return d;
}
__device__ __forceinline__ f32x2 pk_mul(f32x2 a, f32x2 b) {
    f32x2 d; asm("v_pk_mul_f32 %0, %1, %2" : "=v"(d) : "v"(a), "v"(b)); return d;
}
__device__ __forceinline__ f32x2 pk_add(f32x2 a, f32x2 b) {
    f32x2 d; asm("v_pk_add_f32 %0, %1, %2" : "=v"(d) : "v"(a), "v"(b)); return d;
}
// exp2(-|x|) with the abs+neg folded into the VOP3 input modifier (free)
__device__ __forceinline__ float exp_negabs(float x) {
    float r; asm("v_exp_f32_e64 %0, -abs(%1)" : "=v"(r) : "v"(x)); return r;
}
// barrier with LDS-only drain
#define BAR() asm volatile("s_waitcnt lgkmcnt(0)\n\ts_barrier" ::: "memory")

// softplus pair: m = x*log2e ; e = exp2(-|m|) ; q = Estrin cubic ; res = q*e + max(x,0)
__device__ __forceinline__ f32x2 softplus2(f32x2 x, f32x2 PL, f32x2 C1, f32x2 C2, f32x2 C3, f32x2 C4) {
    f32x2 m  = pk_mul(x, PL);                 // +log2e (abs folded into exp)
    f32x2 e;  e.x = exp_negabs(m.x); e.y = exp_negabs(m.y);
    f32x2 e2 = pk_mul(e, e);
    f32x2 qlo = pk_fma(C2, e, C1);
    f32x2 qhi = pk_fma(C4, e, C3);
    f32x2 q   = pk_fma(qhi, e2, qlo);
    f32x2 mx; mx.x = __builtin_fmaxf(x.x, 0.f); mx.y = __builtin_fmaxf(x.y, 0.f);
    return pk_fma(q, e, mx);
}

static __device__ const float TA[5][5] = {
    {0.161f, 0.f, 0.f, 0.f, 0.f},
    {-0.008480655492356989f, 0.335480655492357f, 0.f, 0.f, 0.f},
    {2.8971530571054935f, -6.359448489975075f, 4.3622954328695815f, 0.f, 0.f},
    {5.325864828439257f, -11.748883564062828f, 7.4955393428898365f, -0.09249506636175525f, 0.f},
    {5.86145544294642f, -12.92096931784711f, 8.159367898576159f, -0.071584973281401f, -0.028269050394068383f}
};
static __device__ const float TB[6] = {
    0.09646076681806523f, 0.01f, 0.4798896504144996f,
    1.379008574103742f, -3.290069515436081f, 2.324710524099774f
};

__global__ __launch_bounds__(NTH, 2)
void node_mfma(const float* __restrict__ ts, const float* __restrict__ y0,
               const float* __restrict__ Win, const float* __restrict__ bin,
               const float* __restrict__ Wh, const float* __restrict__ bh,
               const float* __restrict__ Wout, const float* __restrict__ bout,
               float* __restrict__ out)
{
    // activation buffers: chunk-major [16 chunks of 8 feats][16 samples][8 shorts]
    __shared__ __align__(16) short actA[2048];
    __shared__ __align__(16) short actB[2048];
    __shared__ __align__(16) short actC[2048];
    __shared__ __align__(16) float haccL[16 * 132];   // fp32 Hacc staging (cold path)

    const int tid  = threadIdx.x;
    const int wave = tid >> 6;
    const int lane = tid & 63;
    const int n    = lane & 15;
    const int q    = lane >> 4;
    const int r    = 16 * wave + n;       // A-frag matrix row (feature)
    const int fb   = 16 * wave + 4 * q;   // features this lane's D rows cover
    const int s0   = blockIdx.x * 16;

    const int roff = lane * 8;                                           // shorts
    const int woff = (2 * wave + (q >> 1)) * 128 + n * 8 + (q & 1) * 4;  // shorts

    // ---- hidden weight fragments ----
    short8 whf0[4], whf1[4];
    #pragma unroll
    for (int c = 0; c < 4; ++c)
        #pragma unroll
        for (int j = 0; j < 8; ++j) {
            whf0[c][j] = f2bf(Wh[r * 128 + 32 * c + 8 * q + j]);
            whf1[c][j] = f2bf(Wh[16384 + r * 128 + 32 * c + 8 * q + j]);
        }

    // ---- F = Win·Wout fragments, fp32 accumulate then round (once) ----
    short8 ff[4];
    {
        float wrow[32];
        #pragma unroll
        for (int i = 0; i < 8; ++i) *(f32x4*)&wrow[4 * i] = *(const f32x4*)&Win[r * 32 + 4 * i];
        #pragma unroll 1
        for (int c = 0; c < 4; ++c) {
            float facc[8] = {0, 0, 0, 0, 0, 0, 0, 0};
            #pragma unroll
            for (int d = 0; d < 32; ++d) {
                f32x4 wa = *(const f32x4*)&Wout[d * 128 + 32 * c + 8 * q];
                f32x4 wb = *(const f32x4*)&Wout[d * 128 + 32 * c + 8 * q + 4];
                #pragma unroll
                for (int j = 0; j < 4; ++j) { facc[j] += wrow[d] * wa[j]; facc[4 + j] += wrow[d] * wb[j]; }
            }
            #pragma unroll
            for (int j = 0; j < 8; ++j) ff[c][j] = f2bf(facc[j]);
        }
    }

    // ---- c4 = (Win·bout)[fb+rr];  Yb = Win·y0[n] + bin (projected state) ----
    float c4v[4], Yb[4];
    #pragma unroll
    for (int rr = 0; rr < 4; ++rr) {
        const float* wr = &Win[(fb + rr) * 32];
        const float* yr = &y0[(size_t)(s0 + n) * 32];
        float cb = 0.f, yb = 0.f;
        #pragma unroll
        for (int d = 0; d < 32; ++d) { float w = wr[d]; cb += w * bout[d]; yb += w * yr[d]; }
        c4v[rr] = cb;
        Yb[rr]  = yb + bin[fb + rr];
    }
    // bias vectors as MFMA C-init
    f32x4 bhv0, bhv1, c4q;
    #pragma unroll
    for (int rr = 0; rr < 4; ++rr) {
        bhv0[rr] = bh[fb + rr]; bhv1[rr] = bh[128 + fb + rr]; c4q[rr] = c4v[rr];
    }
    const f32x4 Z4 = {0.f, 0.f, 0.f, 0.f};

    // ---- epilogue state split across waves 0 (dims 0-15) and 1 (dims 16-31) ----
    // wave w<2 owns output-dim half ch=w of sample n: y state, bout slice, and
    // the Wout hi/lo fragments for its half (32 VGPR instead of 64, half the tail).
    float yE[4], boE[4];
    short8 WhiE[4], WloE[4];
    if (wave < 2) {
        const int ch = wave;
        f32x4 a = *(const f32x4*)&y0[(size_t)(s0 + n) * 32 + 16 * ch + 4 * q];
        #pragma unroll
        for (int rr = 0; rr < 4; ++rr) {
            yE[rr] = a[rr];
            boE[rr] = bout[16 * ch + 4 * q + rr];
        }
        *(f32x4*)&out[(size_t)(s0 + n) * 4096 + 16 * ch + 4 * q] = a;
        #pragma unroll
        for (int c = 0; c < 4; ++c) {
            f32x4 wa = *(const f32x4*)&Wout[(16 * ch + n) * 128 + 32 * c + 8 * q];
            f32x4 wb = *(const f32x4*)&Wout[(16 * ch + n) * 128 + 32 * c + 8 * q + 4];
            #pragma unroll
            for (int j = 0; j < 4; ++j) {
                short h = f2bf(wa[j]); WhiE[c][j] = h;     WloE[c][j] = f2bf(wa[j] - bf2f(h));
                short g = f2bf(wb[j]); WhiE[c][4 + j] = g; WloE[c][4 + j] = f2bf(wb[j] - bf2f(g));
            }
        }
    }

    // ---- pair-packed state ----
    const f32x2 PL  = {1.44269504088896340736f, 1.44269504088896340736f};
    const f32x2 PC1 = {0.996136f, 0.996136f};
    const f32x2 PC2 = {-0.466224f, -0.466224f};
    const f32x2 PC3 = {0.218528f, 0.218528f};
    const f32x2 PC4 = {-0.055424f, -0.055424f};

    f32x2 Yb2[2] = {{Yb[0], Yb[1]}, {Yb[2], Yb[3]}};
    f32x2 zv2[6][2];
    f32x2 U0 = Yb2[0], U1 = Yb2[1];   // u for the upcoming stage (st=0: u = Yb)

    #pragma unroll 1
    for (int ti = 0; ti < T_SAVE - 1; ++ti) {
        const float hsub = (ts[ti + 1] - ts[ti]) * 0.25f;
        const f32x2 hsubp = {hsub, hsub};
        f32x2 ccp[15];
        {
            int k = 0;
            #pragma unroll
            for (int rr2 = 0; rr2 < 5; ++rr2)
                #pragma unroll
                for (int j = 0; j <= rr2; ++j) {
                    f32x2 t = {TA[rr2][j], TA[rr2][j]};
                    ccp[k++] = pk_mul(hsubp, t);
                }
        }
        f32x2 hbp[6];
        #pragma unroll
        for (int s2 = 0; s2 < 6; ++s2) { f32x2 t = {TB[s2], TB[s2]}; hbp[s2] = pk_mul(hsubp, t); }

        f32x2 HaccA = {0.f, 0.f}, HaccB = {0.f, 0.f};

        #pragma unroll 1
        for (int sub = 0; sub < 4; ++sub) {
            #pragma unroll
            for (int st = 0; st < 6; ++st) {
                // ---- seg A: softplus(u) -> actA ----
                {
                    f32x2 R0 = softplus2(U0, PL, PC1, PC2, PC3, PC4);
                    f32x2 R1 = softplus2(U1, PL, PC1, PC2, PC3, PC4);
                    uint2 pk; pk.x = cvtpk_bf16(R0.x, R0.y); pk.y = cvtpk_bf16(R1.x, R1.y);
                    *(uint2*)(actA + woff) = pk;
                }
                BAR();  // B1

                // ---- seg B: hidden 1: actA -> actB (bias in C-init, 4-acc tree) ----
                {
                    short8 b0 = *(const short8*)(actA + roff);
                    short8 b1 = *(const short8*)(actA + 512 + roff);
                    short8 b2 = *(const short8*)(actA + 1024 + roff);
                    short8 b3 = *(const short8*)(actA + 1536 + roff);
                    f32x4 A0 = __builtin_amdgcn_mfma_f32_16x16x32_bf16(whf0[0], b0, bhv0, 0, 0, 0);
                    f32x4 A1 = __builtin_amdgcn_mfma_f32_16x16x32_bf16(whf0[1], b1, Z4, 0, 0, 0);
                    f32x4 A2 = __builtin_amdgcn_mfma_f32_16x16x32_bf16(whf0[2], b2, Z4, 0, 0, 0);
                    f32x4 A3 = __builtin_amdgcn_mfma_f32_16x16x32_bf16(whf0[3], b3, Z4, 0, 0, 0);
                    f32x4 acc = (A0 + A1) + (A2 + A3);
                    f32x2 h0 = softplus2((f32x2){acc[0], acc[1]}, PL, PC1, PC2, PC3, PC4);
                    f32x2 h1 = softplus2((f32x2){acc[2], acc[3]}, PL, PC1, PC2, PC3, PC4);
                    uint2 pk; pk.x = cvtpk_bf16(h0.x, h0.y); pk.y = cvtpk_bf16(h1.x, h1.y);
                    *(uint2*)(actB + woff) = pk;
                }
                BAR();  // B2

                // ---- seg C: hidden 2: actB -> actC; shadow: u/Yb partial combine ----
                f32x2 P0, P1;
                {
                    short8 b0 = *(const short8*)(actB + roff);
                    short8 b1 = *(const short8*)(actB + 512 + roff);
                    short8 b2 = *(const short8*)(actB + 1024 + roff);
                    short8 b3 = *(const short8*)(actB + 1536 + roff);
                    // shadow-fill the ds_read wait with the already-available combine terms
                    if (st < 5) {
                        P0 = Yb2[0]; P1 = Yb2[1];
                        #pragma unroll
                        for (int j = 0; j < 5; ++j)
                            if (j < st) {
                                const int cb = st * (st + 1) / 2 + j;
                                P0 = pk_fma(ccp[cb], zv2[j][0], P0);
                                P1 = pk_fma(ccp[cb], zv2[j][1], P1);
                            }
                    } else {
                        f32x2 tb0 = {TB[0], TB[0]};
                        P0 = pk_mul(tb0, zv2[0][0]); P1 = pk_mul(tb0, zv2[0][1]);
                        #pragma unroll
                        for (int j = 1; j < 5; ++j) {
                            f32x2 tbj = {TB[j], TB[j]};
                            P0 = pk_fma(tbj, zv2[j][0], P0);
                            P1 = pk_fma(tbj, zv2[j][1], P1);
                        }
                    }
                    f32x4 A0 = __builtin_amdgcn_mfma_f32_16x16x32_bf16(whf1[0], b0, bhv1, 0, 0, 0);
                    f32x4 A1 = __builtin_amdgcn_mfma_f32_16x16x32_bf16(whf1[1], b1, Z4, 0, 0, 0);
                    f32x4 A2 = __builtin_amdgcn_mfma_f32_16x16x32_bf16(whf1[2], b2, Z4, 0, 0, 0);
                    f32x4 A3 = __builtin_amdgcn_mfma_f32_16x16x32_bf16(whf1[3], b3, Z4, 0, 0, 0);
                    f32x4 acc = (A0 + A1) + (A2 + A3);
                    f32x2 h3L = softplus2((f32x2){acc[0], acc[1]}, PL, PC1, PC2, PC3, PC4);
                    f32x2 h3H = softplus2((f32x2){acc[2], acc[3]}, PL, PC1, PC2, PC3, PC4);
                    HaccA = pk_fma(hbp[st], h3L, HaccA);
                    HaccB = pk_fma(hbp[st], h3H, HaccB);
                    uint2 pk; pk.x = cvtpk_bf16(h3L.x, h3L.y); pk.y = cvtpk_bf16(h3H.x, h3H.y);
                    *(uint2*)(actC + woff) = pk;
                }
                BAR();  // B3

                // ---- seg D: fused layer z = F·h3 + c4 (C-init); finish u / Yb ----
                {
                    short8 b0 = *(const short8*)(actC + roff);
                    short8 b1 = *(const short8*)(actC + 512 + roff);
                    short8 b2 = *(const short8*)(actC + 1024 + roff);
                    short8 b3 = *(const short8*)(actC + 1536 + roff);
                    f32x4 A0 = __builtin_amdgcn_mfma_f32_16x16x32_bf16(ff[0], b0, c4q, 0, 0, 0);
                    f32x4 A1 = __builtin_amdgcn_mfma_f32_16x16x32_bf16(ff[1], b1, Z4, 0, 0, 0);
                    f32x4 A2 = __builtin_amdgcn_mfma_f32_16x16x32_bf16(ff[2], b2, Z4, 0, 0, 0);
                    f32x4 A3 = __builtin_amdgcn_mfma_f32_16x16x32_bf16(ff[3], b3, Z4, 0, 0, 0);
                    f32x4 acc = (A0 + A1) + (A2 + A3);
                    f32x2 zL = {acc[0], acc[1]};
                    f32x2 zH = {acc[2], acc[3]};
                    zv2[st][0] = zL; zv2[st][1] = zH;
                    if (st < 5) {
                        const int cb = st * (st + 1) / 2 + st;
                        U0 = pk_fma(ccp[cb], zL, P0);
                        U1 = pk_fma(ccp[cb], zH, P1);
                    } else {
                        f32x2 tb5 = {TB[5], TB[5]};
                        P0 = pk_fma(tb5, zL, P0); P1 = pk_fma(tb5, zH, P1);
                        Yb2[0] = pk_fma(hsubp, P0, Yb2[0]);
                        Yb2[1] = pk_fma(hsubp, P1, Yb2[1]);
                        U0 = Yb2[0]; U1 = Yb2[1];
                    }
                }
            }
        }

        // ---- interval end: y += Wout·Hacc_total + 4h·bout (waves 0+1, hi/lo exact) ----
        {
            f32x4 hv; hv[0] = HaccA.x; hv[1] = HaccA.y; hv[2] = HaccB.x; hv[3] = HaccB.y;
            *(f32x4*)(haccL + n * 132 + fb) = hv;
        }
        BAR();
        if (wave < 2) {
            f32x4 dd = {0.f, 0.f, 0.f, 0.f};
            #pragma unroll
            for (int c = 0; c < 4; ++c) {
                f32x4 ha  = *(const f32x4*)(haccL + n * 132 + 32 * c + 8 * q);
                f32x4 hb2 = *(const f32x4*)(haccL + n * 132 + 32 * c + 8 * q + 4);
                short8 Hhi, Hlo;
                #pragma unroll
                for (int j = 0; j < 4; ++j) {
                    short h = f2bf(ha[j]);  Hhi[j] = h;     Hlo[j] = f2bf(ha[j] - bf2f(h));
                    short g = f2bf(hb2[j]); Hhi[4 + j] = g; Hlo[4 + j] = f2bf(hb2[j] - bf2f(g));
                }
                dd = __builtin_amdgcn_mfma_f32_16x16x32_bf16(WhiE[c], Hhi, dd, 0, 0, 0);
                dd = __builtin_amdgcn_mfma_f32_16x16x32_bf16(WhiE[c], Hlo, dd, 0, 0, 0);
                dd = __builtin_amdgcn_mfma_f32_16x16x32_bf16(WloE[c], Hhi, dd, 0, 0, 0);
            }
            const float hb4 = 4.f * hsub;
            f32x4 o;
            #pragma unroll
            for (int rr = 0; rr < 4; ++rr) {
                yE[rr] += dd[rr] + hb4 * boE[rr];
                o[rr] = yE[rr];
            }
            *(f32x4*)&out[(size_t)(s0 + n) * 4096 + (ti + 1) * 32 + 16 * wave + 4 * q] = o;
        }
    }
}

extern "C" void kernel_launch(void* const* d_in, const int* in_sizes, int n_in,
                              void* d_out, int out_size, void* d_ws, size_t ws_size,
                              hipStream_t stream) {
    const float* ts   = (const float*)d_in[0];
    const float* y0   = (const float*)d_in[1];
    const float* Win  = (const float*)d_in[2];
    const float* bin  = (const float*)d_in[3];
    const float* Wh   = (const float*)d_in[4];
    const float* bh   = (const float*)d_in[5];
    const float* Wout = (const float*)d_in[6];
    const float* bout = (const float*)d_in[7];
    float* out = (float*)d_out;

    const int Btot = in_sizes[1] / 32;  // 4096 samples
    dim3 grid(Btot / 16), block(NTH);   // 256 blocks x 512 threads, 1 block/CU
    node_mfma<<<grid, block, 0, stream>>>(ts, y0, Win, bin, Wh, bh, Wout, bout, out);
}